// Round 1
// baseline (671.925 us; speedup 1.0000x reference)
//
#include <hip/hip_runtime.h>

// Problem dims
// images [64,256,256,3] f32 NHWC; output flow [64,2,64,64] f32
// conv1: 3->32 k5 s2 p2 relu -> [64,32,128,128]
// conv2: 32->32 k5 s2 p2 relu -> [64,32,64,64]
// MLP:   4->256 relu ->800 -> per-sample kernels [64,32,5,5]
// xconv: depthwise per-sample k5 p2 -> [64,32,64,64]
// mp1:   32->32 k3 p1 relu
// mp2:   32->2  k3 p1

__device__ __forceinline__ int iclamp(int v, int lo, int hi) {
    return v < lo ? lo : (v > hi ? hi : v);
}

// Repack weights src[o][i][t] (O,I,T) -> dst[(i*T+t)*O + o]
__global__ __launch_bounds__(256) void repack_kernel(const float* __restrict__ src,
                                                     float* __restrict__ dst,
                                                     int O, int I, int T) {
    int idx = blockIdx.x * 256 + threadIdx.x;
    int total = O * I * T;
    if (idx >= total) return;
    int it = I * T;
    int o = idx / it;
    int r = idx - o * it;
    dst[r * O + o] = src[idx];
}

// Action MLP: actions[64,4] -> hidden[256] relu -> out[800]
__global__ __launch_bounds__(256) void mlp_kernel(const float* __restrict__ actions,
                                                  const float* __restrict__ w1,
                                                  const float* __restrict__ b1,
                                                  const float* __restrict__ w2,
                                                  const float* __restrict__ b2,
                                                  float* __restrict__ aout) {
    int n = blockIdx.x;
    int t = threadIdx.x; // 0..255
    __shared__ float hid[256];
    float a0 = actions[n * 4 + 0], a1 = actions[n * 4 + 1];
    float a2 = actions[n * 4 + 2], a3 = actions[n * 4 + 3];
    float acc = b1[t];
    acc += a0 * w1[0 * 256 + t] + a1 * w1[1 * 256 + t] +
           a2 * w1[2 * 256 + t] + a3 * w1[3 * 256 + t];
    hid[t] = fmaxf(acc, 0.0f);
    __syncthreads();
    for (int o = t; o < 800; o += 256) {
        float s = b2[o];
        #pragma unroll 4
        for (int i = 0; i < 256; ++i) s += hid[i] * w2[i * 800 + o];
        aout[n * 800 + o] = s;
    }
}

// conv1: img NHWC [64,256,256,3] -> h1 [64,32,128,128], k5 s2 p2, relu
// wT layout [(c*25+tap)*32 + o]
__global__ __launch_bounds__(256) void conv1_kernel(const float* __restrict__ img,
                                                    const float* __restrict__ wT,
                                                    const float* __restrict__ bias,
                                                    float* __restrict__ out) {
    const int ox = threadIdx.x;                    // 0..127
    const int oy = blockIdx.x * 2 + threadIdx.y;   // 0..127
    const int n = blockIdx.y;
    float acc[32];
    #pragma unroll
    for (int o = 0; o < 32; ++o) acc[o] = bias[o];

    #pragma unroll
    for (int kh = 0; kh < 5; ++kh) {
        const int iy = 2 * oy - 2 + kh;
        if (iy < 0 || iy >= 256) continue;   // wave-uniform
        const float* rowp = img + ((size_t)n * 256 + iy) * 256 * 3;
        #pragma unroll
        for (int kw = 0; kw < 5; ++kw) {
            const int ix = 2 * ox - 2 + kw;
            const int ixc = iclamp(ix, 0, 255);
            const float* p = rowp + (size_t)ixc * 3;
            float v0 = p[0], v1 = p[1], v2 = p[2];
            if (ix != ixc) { v0 = 0.0f; v1 = 0.0f; v2 = 0.0f; }
            const int tap = kh * 5 + kw;
            const float* w0 = wT + (0 * 25 + tap) * 32;
            const float* w1 = wT + (1 * 25 + tap) * 32;
            const float* w2 = wT + (2 * 25 + tap) * 32;
            #pragma unroll
            for (int o = 0; o < 32; ++o)
                acc[o] += w0[o] * v0 + w1[o] * v1 + w2[o] * v2;
        }
    }
    size_t base = (size_t)n * 32 * 16384 + (size_t)oy * 128 + ox;
    #pragma unroll
    for (int o = 0; o < 32; ++o)
        out[base + (size_t)o * 16384] = fmaxf(acc[o], 0.0f);
}

// conv2: h1 [64,32,128,128] -> h2 [64,32,64,64], k5 s2 p2, relu
// wT layout [(ci*25+tap)*32 + o]
__global__ __launch_bounds__(256) void conv2_kernel(const float* __restrict__ in,
                                                    const float* __restrict__ wT,
                                                    const float* __restrict__ bias,
                                                    float* __restrict__ out) {
    const int ox = threadIdx.x;                    // 0..63
    const int oy = blockIdx.x * 4 + threadIdx.y;   // 0..63
    const int n = blockIdx.y;
    float acc[32];
    #pragma unroll
    for (int o = 0; o < 32; ++o) acc[o] = bias[o];

    const float* inn = in + (size_t)n * 32 * 16384;
    for (int ci = 0; ci < 32; ++ci) {
        const float* ip = inn + (size_t)ci * 16384;
        const float* wci = wT + ci * 25 * 32;
        #pragma unroll
        for (int kh = 0; kh < 5; ++kh) {
            const int iy = 2 * oy - 2 + kh;
            if (iy < 0 || iy >= 128) continue;  // wave-uniform
            const float* row = ip + (size_t)iy * 128;
            #pragma unroll
            for (int kw = 0; kw < 5; ++kw) {
                const int ix = 2 * ox - 2 + kw;
                const int ixc = iclamp(ix, 0, 127);
                float v = row[ixc];
                if (ix != ixc) v = 0.0f;
                const float* wp = wci + (kh * 5 + kw) * 32;
                #pragma unroll
                for (int o = 0; o < 32; ++o) acc[o] += wp[o] * v;
            }
        }
    }
    size_t base = (size_t)n * 32 * 4096 + (size_t)oy * 64 + ox;
    #pragma unroll
    for (int o = 0; o < 32; ++o)
        out[base + (size_t)o * 4096] = fmaxf(acc[o], 0.0f);
}

// cross-conv: h2 [64,32,64,64] (x) kernels [64*32,25], k5 p2 s1, no bias/relu
__global__ __launch_bounds__(256) void xconv_kernel(const float* __restrict__ in,
                                                    const float* __restrict__ ker,
                                                    float* __restrict__ out) {
    const int ox = threadIdx.x;                    // 0..63
    const int oy = blockIdx.x * 4 + threadIdx.y;   // 0..63
    const int nc = blockIdx.y;                     // 0..2047
    const float* ip = in + (size_t)nc * 4096;
    const float* kp = ker + (size_t)nc * 25;
    float acc = 0.0f;
    #pragma unroll
    for (int kh = 0; kh < 5; ++kh) {
        const int iy = oy - 2 + kh;
        if (iy < 0 || iy >= 64) continue;  // wave-uniform
        const float* row = ip + (size_t)iy * 64;
        #pragma unroll
        for (int kw = 0; kw < 5; ++kw) {
            const int ix = ox - 2 + kw;
            const int ixc = iclamp(ix, 0, 63);
            float v = row[ixc];
            if (ix != ixc) v = 0.0f;
            acc += kp[kh * 5 + kw] * v;
        }
    }
    out[(size_t)nc * 4096 + (size_t)oy * 64 + ox] = acc;
}

// mp1: sa [64,32,64,64] -> f [64,32,64,64], k3 p1, relu
// wT layout [(ci*9+tap)*32 + o]
__global__ __launch_bounds__(256) void mp1_kernel(const float* __restrict__ in,
                                                  const float* __restrict__ wT,
                                                  const float* __restrict__ bias,
                                                  float* __restrict__ out) {
    const int ox = threadIdx.x;                    // 0..63
    const int oy = blockIdx.x * 4 + threadIdx.y;   // 0..63
    const int n = blockIdx.y;
    float acc[32];
    #pragma unroll
    for (int o = 0; o < 32; ++o) acc[o] = bias[o];

    const float* inn = in + (size_t)n * 32 * 4096;
    for (int ci = 0; ci < 32; ++ci) {
        const float* ip = inn + (size_t)ci * 4096;
        const float* wci = wT + ci * 9 * 32;
        #pragma unroll
        for (int kh = 0; kh < 3; ++kh) {
            const int iy = oy - 1 + kh;
            if (iy < 0 || iy >= 64) continue;  // wave-uniform
            const float* row = ip + (size_t)iy * 64;
            #pragma unroll
            for (int kw = 0; kw < 3; ++kw) {
                const int ix = ox - 1 + kw;
                const int ixc = iclamp(ix, 0, 63);
                float v = row[ixc];
                if (ix != ixc) v = 0.0f;
                const float* wp = wci + (kh * 3 + kw) * 32;
                #pragma unroll
                for (int o = 0; o < 32; ++o) acc[o] += wp[o] * v;
            }
        }
    }
    size_t base = (size_t)n * 32 * 4096 + (size_t)oy * 64 + ox;
    #pragma unroll
    for (int o = 0; o < 32; ++o)
        out[base + (size_t)o * 4096] = fmaxf(acc[o], 0.0f);
}

// mp2: f [64,32,64,64] -> flow [64,2,64,64], k3 p1, no relu
// wT layout [(ci*9+tap)*2 + o]
__global__ __launch_bounds__(256) void mp2_kernel(const float* __restrict__ in,
                                                  const float* __restrict__ wT,
                                                  const float* __restrict__ bias,
                                                  float* __restrict__ out) {
    const int ox = threadIdx.x;                    // 0..63
    const int oy = blockIdx.x * 4 + threadIdx.y;   // 0..63
    const int n = blockIdx.y;
    float a0 = bias[0], a1 = bias[1];

    const float* inn = in + (size_t)n * 32 * 4096;
    for (int ci = 0; ci < 32; ++ci) {
        const float* ip = inn + (size_t)ci * 4096;
        const float* wci = wT + ci * 18;
        #pragma unroll
        for (int kh = 0; kh < 3; ++kh) {
            const int iy = oy - 1 + kh;
            if (iy < 0 || iy >= 64) continue;  // wave-uniform
            const float* row = ip + (size_t)iy * 64;
            #pragma unroll
            for (int kw = 0; kw < 3; ++kw) {
                const int ix = ox - 1 + kw;
                const int ixc = iclamp(ix, 0, 63);
                float v = row[ixc];
                if (ix != ixc) v = 0.0f;
                const float* wp = wci + (kh * 3 + kw) * 2;
                a0 += wp[0] * v;
                a1 += wp[1] * v;
            }
        }
    }
    size_t base = (size_t)n * 2 * 4096 + (size_t)oy * 64 + ox;
    out[base] = a0;
    out[base + 4096] = a1;
}

extern "C" void kernel_launch(void* const* d_in, const int* in_sizes, int n_in,
                              void* d_out, int out_size, void* d_ws, size_t ws_size,
                              hipStream_t stream) {
    (void)in_sizes; (void)n_in; (void)out_size; (void)ws_size;
    const float* images  = (const float*)d_in[0];
    const float* actions = (const float*)d_in[1];
    const float* pe_w1   = (const float*)d_in[2];
    const float* pe_b1   = (const float*)d_in[3];
    const float* pe_w2   = (const float*)d_in[4];
    const float* pe_b2   = (const float*)d_in[5];
    const float* ae_w1   = (const float*)d_in[6];
    const float* ae_b1   = (const float*)d_in[7];
    const float* ae_w2   = (const float*)d_in[8];
    const float* ae_b2   = (const float*)d_in[9];
    const float* mp_w1   = (const float*)d_in[10];
    const float* mp_b1   = (const float*)d_in[11];
    const float* mp_w2   = (const float*)d_in[12];
    const float* mp_b2   = (const float*)d_in[13];
    float* out = (float*)d_out;

    char* ws = (char*)d_ws;
    float* a_ker = (float*)(ws + 0);            // 64*800*4      = 204800
    float* w1T   = (float*)(ws + 204800);       // 2400*4        = 9600
    float* w2T   = (float*)(ws + 214400);       // 25600*4       = 102400
    float* mp1T  = (float*)(ws + 316800);       // 9216*4        = 36864
    float* mp2T  = (float*)(ws + 353664);       // 576*4         = 2304
    float* h1    = (float*)(ws + 524288);       // 64*32*128*128*4 = 134217728
    float* h2    = (float*)(ws + 524288 + 134217728); // 64*32*64*64*4 = 33554432
    float* sa    = h1;                          // reuse h1 region (dead after conv2)
    float* f     = (float*)((char*)h1 + 33554432);

    repack_kernel<<<10, 256, 0, stream>>>(pe_w1, w1T, 32, 3, 25);
    repack_kernel<<<100, 256, 0, stream>>>(pe_w2, w2T, 32, 32, 25);
    repack_kernel<<<36, 256, 0, stream>>>(mp_w1, mp1T, 32, 32, 9);
    repack_kernel<<<3, 256, 0, stream>>>(mp_w2, mp2T, 2, 32, 9);

    mlp_kernel<<<64, 256, 0, stream>>>(actions, ae_w1, ae_b1, ae_w2, ae_b2, a_ker);
    conv1_kernel<<<dim3(64, 64), dim3(128, 2), 0, stream>>>(images, w1T, pe_b1, h1);
    conv2_kernel<<<dim3(16, 64), dim3(64, 4), 0, stream>>>(h1, w2T, pe_b2, h2);
    xconv_kernel<<<dim3(16, 2048), dim3(64, 4), 0, stream>>>(h2, a_ker, sa);
    mp1_kernel<<<dim3(16, 64), dim3(64, 4), 0, stream>>>(sa, mp1T, mp_b1, f);
    mp2_kernel<<<dim3(16, 64), dim3(64, 4), 0, stream>>>(f, mp2T, mp_b2, out);
}